// Round 1
// baseline (175.777 us; speedup 1.0000x reference)
//
#include <hip/hip_runtime.h>
#include <hip/hip_bf16.h>

// Problem constants
#define B_  8
#define C_  64
#define H_  256
#define W_  256
#define HW_ (H_ * W_)
#define NP_ 25          // NUM_POINTS
#define NA_ 28          // N + 3 (augmented TPS system size)
#define NRHS_ 16        // 8 batches x 2 coords
#define NCOL_ (NA_ + NRHS_)   // 44

// ---------------------------------------------------------------------------
// Kernel 1: per-(b,c) mean over HxW of concat([t, rgb], axis=1) -> feat[8*128]
// ---------------------------------------------------------------------------
__global__ __launch_bounds__(256) void mean_kernel(const float* __restrict__ t,
                                                   const float* __restrict__ rgb,
                                                   float* __restrict__ feat) {
    int blk = blockIdx.x;              // b*128 + c
    int b = blk >> 7;
    int c = blk & 127;
    const float* src = (c < C_) ? (t   + ((size_t)b * C_ + c)        * HW_)
                                : (rgb + ((size_t)b * C_ + (c - C_)) * HW_);
    const float4* src4 = (const float4*)src;
    float s = 0.f;
    for (int i = threadIdx.x; i < HW_ / 4; i += 256) {
        float4 v = src4[i];
        s += (v.x + v.y) + (v.z + v.w);
    }
    __shared__ float red[256];
    red[threadIdx.x] = s;
    __syncthreads();
    for (int off = 128; off > 0; off >>= 1) {
        if (threadIdx.x < off) red[threadIdx.x] += red[threadIdx.x + off];
        __syncthreads();
    }
    if (threadIdx.x == 0) feat[blk] = red[0] * (1.0f / (float)HW_);
}

// ---------------------------------------------------------------------------
// Kernel 2: delta = feat @ fc_w^T + fc_b ; cp = init_cp + delta (written to
// d_out tail); build TPS L (28x28, f64) and Gauss-Jordan solve L X = Y for
// all 8 batches x 2 coords at once -> Wm[8][28][2] (f64) in workspace.
// ---------------------------------------------------------------------------
__global__ __launch_bounds__(256) void solve_kernel(const float* __restrict__ feat,
                                                    const float* __restrict__ fc_w,
                                                    const float* __restrict__ fc_b,
                                                    const float* __restrict__ init_cp,
                                                    float* __restrict__ cp_out,
                                                    double* __restrict__ Wm) {
    __shared__ float  s_cp[B_][2 * NP_];
    __shared__ double P[NP_][2];
    __shared__ double A[NA_][NCOL_];
    __shared__ double f[NA_];
    __shared__ int    s_piv;
    __shared__ double s_pv;
    int tid = threadIdx.x;

    // Phase A: cp = init_cp + (feat @ fc_w^T + fc_b)
    for (int i = tid; i < B_ * 2 * NP_; i += 256) {
        int b = i / (2 * NP_), j = i % (2 * NP_);
        float acc = fc_b[j];
        const float* w  = fc_w + j * 128;
        const float* fe = feat + b * 128;
        #pragma unroll 8
        for (int c = 0; c < 128; ++c) acc += fe[c] * w[c];
        float cpv = init_cp[j] + acc;
        s_cp[b][j] = cpv;
        cp_out[b * 2 * NP_ + j] = cpv;   // second tuple output (f32)
    }
    if (tid < 2 * NP_) ((double*)P)[tid] = (double)init_cp[tid];
    __syncthreads();

    // Phase B: build augmented [L | Y]
    for (int i = tid; i < NA_ * NCOL_; i += 256) {
        int r = i / NCOL_, cc = i % NCOL_;
        double v;
        if (cc < NA_) {
            if (r < NP_ && cc < NP_) {
                double dx = P[r][0] - P[cc][0];
                double dy = P[r][1] - P[cc][1];
                double d2 = dx * dx + dy * dy;
                v = d2 * log(d2 + 1e-6);
            } else if (r < NP_) {
                v = (cc == NP_) ? 1.0 : ((cc == NP_ + 1) ? P[r][0] : P[r][1]);
            } else if (cc < NP_) {
                v = (r == NP_) ? 1.0 : ((r == NP_ + 1) ? P[cc][0] : P[cc][1]);
            } else {
                v = 0.0;
            }
        } else {
            int y = cc - NA_;           // b*2 + k
            int b = y >> 1, k = y & 1;
            v = (r < NP_) ? (double)s_cp[b][r * 2 + k] : 0.0;
        }
        A[r][cc] = v;
    }
    __syncthreads();

    // Phase C: Gauss-Jordan with partial pivoting (f64)
    for (int k = 0; k < NA_; ++k) {
        if (tid == 0) {
            int piv = k; double best = fabs(A[k][k]);
            for (int r = k + 1; r < NA_; ++r) {
                double v = fabs(A[r][k]);
                if (v > best) { best = v; piv = r; }
            }
            s_piv = piv;
        }
        __syncthreads();
        int piv = s_piv;
        if (piv != k) {
            for (int j = tid; j < NCOL_; j += 256) {
                double tmp = A[k][j]; A[k][j] = A[piv][j]; A[piv][j] = tmp;
            }
        }
        __syncthreads();
        if (tid == 0) s_pv = 1.0 / A[k][k];
        __syncthreads();
        double pv = s_pv;
        for (int j = tid; j < NCOL_; j += 256) A[k][j] *= pv;
        __syncthreads();
        if (tid < NA_) f[tid] = A[tid][k];
        __syncthreads();
        for (int i = tid; i < NA_ * NCOL_; i += 256) {
            int r = i / NCOL_, j = i % NCOL_;
            if (r != k) A[r][j] -= f[r] * A[k][j];
        }
        __syncthreads();
    }

    // Phase D: write Wm[b][n][c]
    for (int i = tid; i < B_ * NA_ * 2; i += 256) {
        int b = i / (NA_ * 2), rest = i % (NA_ * 2);
        int n = rest >> 1, c = rest & 1;
        Wm[i] = A[n][NA_ + b * 2 + c];
    }
}

// ---------------------------------------------------------------------------
// Kernel 3: fused TPS grid evaluation (f64, matching reference) + bilinear
// grid_sample (f32, border padding, align_corners=True) over all 64 channels.
// One thread per (b, y, x) pixel.
// ---------------------------------------------------------------------------
__global__ __launch_bounds__(256) void grid_sample_kernel(const float* __restrict__ t,
                                                          const float* __restrict__ init_cp,
                                                          const double* __restrict__ Wm,
                                                          float* __restrict__ out) {
    int blk = blockIdx.x;   // b*H + y
    int b = blk >> 8;
    int y = blk & 255;
    int x = threadIdx.x;

    __shared__ double sP[NP_][2];
    __shared__ double sW[NA_][2];
    if (threadIdx.x < 2 * NP_)
        ((double*)sP)[threadIdx.x] = (double)init_cp[threadIdx.x];
    else if (threadIdx.x < 2 * NP_ + 2 * NA_)
        ((double*)sW)[threadIdx.x - 2 * NP_] = Wm[(size_t)b * 2 * NA_ + (threadIdx.x - 2 * NP_)];
    __syncthreads();

    // grid point (gx[x], gy[y]) in f64
    double px = -1.0 + 2.0 * (double)x / (double)(W_ - 1);
    double py = -1.0 + 2.0 * (double)y / (double)(H_ - 1);

    double ax = sW[NP_][0] + px * sW[NP_ + 1][0] + py * sW[NP_ + 2][0];
    double ay = sW[NP_][1] + px * sW[NP_ + 1][1] + py * sW[NP_ + 2][1];
    #pragma unroll
    for (int n = 0; n < NP_; ++n) {
        double dx = px - sP[n][0];
        double dy = py - sP[n][1];
        double d2 = dx * dx + dy * dy;
        double u  = d2 * log(d2 + 1e-6);
        ax += u * sW[n][0];
        ay += u * sW[n][1];
    }
    float gx = (float)ax;
    float gy = (float)ay;

    // bilinear sample, border clamp, align_corners=True (f32, like reference)
    float xf = fminf(fmaxf((gx + 1.0f) * 0.5f * (float)(W_ - 1), 0.0f), (float)(W_ - 1));
    float yf = fminf(fmaxf((gy + 1.0f) * 0.5f * (float)(H_ - 1), 0.0f), (float)(H_ - 1));
    float x0f = floorf(xf), y0f = floorf(yf);
    int x0 = (int)x0f, y0 = (int)y0f;
    int x1 = min(x0 + 1, W_ - 1);
    int y1 = min(y0 + 1, H_ - 1);
    float wx = xf - x0f, wy = yf - y0f;
    float omwx = 1.0f - wx, omwy = 1.0f - wy;

    int i00 = y0 * W_ + x0;
    int i01 = y0 * W_ + x1;
    int i10 = y1 * W_ + x0;
    int i11 = y1 * W_ + x1;

    const float* tb = t   + (size_t)b * C_ * HW_;
    float*       ob = out + (size_t)b * C_ * HW_ + y * W_ + x;
    #pragma unroll 4
    for (int c = 0; c < C_; ++c) {
        const float* tc = tb + (size_t)c * HW_;
        float top = tc[i00] * omwx + tc[i01] * wx;
        float bot = tc[i10] * omwx + tc[i11] * wx;
        ob[(size_t)c * HW_] = top * omwy + bot * wy;
    }
}

// ---------------------------------------------------------------------------
extern "C" void kernel_launch(void* const* d_in, const int* in_sizes, int n_in,
                              void* d_out, int out_size, void* d_ws, size_t ws_size,
                              hipStream_t stream) {
    const float* t       = (const float*)d_in[0];
    const float* rgb     = (const float*)d_in[1];
    const float* fc_w    = (const float*)d_in[2];
    const float* fc_b    = (const float*)d_in[3];
    const float* init_cp = (const float*)d_in[4];

    float* out    = (float*)d_out;
    float* cp_out = out + (size_t)B_ * C_ * HW_;   // tuple output #2

    float*  feat = (float*)d_ws;                       // 1024 f32
    double* Wm   = (double*)((char*)d_ws + 4096);      // 8*28*2 f64

    mean_kernel<<<B_ * 2 * C_, 256, 0, stream>>>(t, rgb, feat);
    solve_kernel<<<1, 256, 0, stream>>>(feat, fc_w, fc_b, init_cp, cp_out, Wm);
    grid_sample_kernel<<<B_ * H_, 256, 0, stream>>>(t, init_cp, Wm, out);
}

// Round 2
// 173.858 us; speedup vs baseline: 1.0110x; 1.0110x over previous
//
#include <hip/hip_runtime.h>
#include <hip/hip_bf16.h>

// Problem constants
#define B_  8
#define C_  64
#define H_  256
#define W_  256
#define HW_ (H_ * W_)
#define NP_ 25          // NUM_POINTS
#define NA_ 28          // N + 3 (augmented TPS system size)
#define NRHS_ 16        // 8 batches x 2 coords
#define NCOL_ (NA_ + NRHS_)   // 44
#define PARTS_ 8              // chunks per channel for the mean pass
#define CHUNK_ (HW_ / PARTS_) // 8192 floats per chunk

// ---------------------------------------------------------------------------
// Kernel 1: partial sums for per-(b,c) mean of concat([t, rgb], axis=1).
// 8192 blocks: first 4096 cover rgb channels, last 4096 cover t channels
// (so t is fetched last and stays L3-resident for the sample kernel).
// Each block sums one 8192-float chunk; 8 float4 loads in flight per thread.
// ---------------------------------------------------------------------------
__global__ __launch_bounds__(256) void mean_partial_kernel(const float* __restrict__ t,
                                                           const float* __restrict__ rgb,
                                                           float* __restrict__ partial) {
    int blk  = blockIdx.x;              // 0..8191
    bool is_t = blk >= 4096;
    int idx  = (is_t ? blk - 4096 : blk) >> 3;   // 0..511 channel-local index
    int part = blk & 7;
    int b    = idx >> 6;
    int cloc = idx & 63;
    int chan = b * 128 + (is_t ? cloc : 64 + cloc);   // feat layout: [t | rgb]

    const float* src = (is_t ? t : rgb) + ((size_t)(b * C_ + cloc)) * HW_ + part * CHUNK_;
    const float4* s4 = (const float4*)src;

    float s = 0.f;
    int base = threadIdx.x;
    #pragma unroll
    for (int i = 0; i < CHUNK_ / 4 / 256; ++i) {      // 8 fully-unrolled iters
        float4 v = s4[base + i * 256];
        s += (v.x + v.y) + (v.z + v.w);
    }
    // wave-level reduce (wave = 64)
    #pragma unroll
    for (int off = 32; off > 0; off >>= 1) s += __shfl_down(s, off);
    __shared__ float red[4];
    if ((threadIdx.x & 63) == 0) red[threadIdx.x >> 6] = s;
    __syncthreads();
    if (threadIdx.x == 0)
        partial[chan * PARTS_ + part] = (red[0] + red[1]) + (red[2] + red[3]);
}

// ---------------------------------------------------------------------------
// Kernel 2: reduce partials -> feat; delta = feat @ fc_w^T + fc_b;
// cp = init_cp + delta (written to d_out tail); build TPS L (28x28, f64) and
// Gauss-Jordan solve for all 8 batches x 2 coords -> Wm[8][28][2] f64 in ws.
// ---------------------------------------------------------------------------
__global__ __launch_bounds__(256) void solve_kernel(const float* __restrict__ partial,
                                                    const float* __restrict__ fc_w,
                                                    const float* __restrict__ fc_b,
                                                    const float* __restrict__ init_cp,
                                                    float* __restrict__ cp_out,
                                                    double* __restrict__ Wm) {
    __shared__ float  s_feat[B_ * 128];
    __shared__ float  s_cp[B_][2 * NP_];
    __shared__ double P[NP_][2];
    __shared__ double A[NA_][NCOL_];
    __shared__ double f[NA_];
    __shared__ int    s_piv;
    __shared__ double s_pv;
    int tid = threadIdx.x;

    // Phase 0: deterministic fixed-order reduction of partials -> feat
    for (int i = tid; i < B_ * 128; i += 256) {
        const float* p = partial + i * PARTS_;
        float s = 0.f;
        #pragma unroll
        for (int j = 0; j < PARTS_; ++j) s += p[j];
        s_feat[i] = s * (1.0f / (float)HW_);
    }
    if (tid < 2 * NP_) ((double*)P)[tid] = (double)init_cp[tid];
    __syncthreads();

    // Phase A: cp = init_cp + (feat @ fc_w^T + fc_b)
    for (int i = tid; i < B_ * 2 * NP_; i += 256) {
        int b = i / (2 * NP_), j = i % (2 * NP_);
        float acc = fc_b[j];
        const float* w  = fc_w + j * 128;
        const float* fe = s_feat + b * 128;
        #pragma unroll 8
        for (int c = 0; c < 128; ++c) acc += fe[c] * w[c];
        float cpv = init_cp[j] + acc;
        s_cp[b][j] = cpv;
        cp_out[b * 2 * NP_ + j] = cpv;   // second tuple output (f32)
    }
    __syncthreads();

    // Phase B: build augmented [L | Y]
    for (int i = tid; i < NA_ * NCOL_; i += 256) {
        int r = i / NCOL_, cc = i % NCOL_;
        double v;
        if (cc < NA_) {
            if (r < NP_ && cc < NP_) {
                double dx = P[r][0] - P[cc][0];
                double dy = P[r][1] - P[cc][1];
                double d2 = dx * dx + dy * dy;
                v = d2 * log(d2 + 1e-6);
            } else if (r < NP_) {
                v = (cc == NP_) ? 1.0 : ((cc == NP_ + 1) ? P[r][0] : P[r][1]);
            } else if (cc < NP_) {
                v = (r == NP_) ? 1.0 : ((r == NP_ + 1) ? P[cc][0] : P[cc][1]);
            } else {
                v = 0.0;
            }
        } else {
            int y = cc - NA_;           // b*2 + k
            int b = y >> 1, k = y & 1;
            v = (r < NP_) ? (double)s_cp[b][r * 2 + k] : 0.0;
        }
        A[r][cc] = v;
    }
    __syncthreads();

    // Phase C: Gauss-Jordan with partial pivoting (f64)
    for (int k = 0; k < NA_; ++k) {
        if (tid == 0) {
            int piv = k; double best = fabs(A[k][k]);
            for (int r = k + 1; r < NA_; ++r) {
                double v = fabs(A[r][k]);
                if (v > best) { best = v; piv = r; }
            }
            s_piv = piv;
        }
        __syncthreads();
        int piv = s_piv;
        if (piv != k) {
            for (int j = tid; j < NCOL_; j += 256) {
                double tmp = A[k][j]; A[k][j] = A[piv][j]; A[piv][j] = tmp;
            }
        }
        __syncthreads();
        if (tid == 0) s_pv = 1.0 / A[k][k];
        __syncthreads();
        double pv = s_pv;
        for (int j = tid; j < NCOL_; j += 256) A[k][j] *= pv;
        __syncthreads();
        if (tid < NA_) f[tid] = A[tid][k];
        __syncthreads();
        for (int i = tid; i < NA_ * NCOL_; i += 256) {
            int r = i / NCOL_, j = i % NCOL_;
            if (r != k) A[r][j] -= f[r] * A[k][j];
        }
        __syncthreads();
    }

    // Phase D: write Wm[b][n][c]
    for (int i = tid; i < B_ * NA_ * 2; i += 256) {
        int b = i / (NA_ * 2), rest = i % (NA_ * 2);
        int n = rest >> 1, c = rest & 1;
        Wm[i] = A[n][NA_ + b * 2 + c];
    }
}

// ---------------------------------------------------------------------------
// Kernel 3: fused TPS grid evaluation (f32 basis — error << threshold since
// non-affine weights are ~1e-3) + bilinear grid_sample (border, align_corners)
// over all 64 channels. One thread per (b, y, x) pixel.
// ---------------------------------------------------------------------------
__global__ __launch_bounds__(256) void sample_kernel(const float* __restrict__ t,
                                                     const float* __restrict__ init_cp,
                                                     const double* __restrict__ Wm,
                                                     float* __restrict__ out) {
    int blk = blockIdx.x;   // b*H + y
    int b = blk >> 8;
    int y = blk & 255;
    int x = threadIdx.x;

    __shared__ float sW[NA_][2];
    __shared__ float sP[NP_][2];
    if (x < 2 * NA_)
        ((float*)sW)[x] = (float)Wm[(size_t)b * 2 * NA_ + x];
    else if (x < 2 * NA_ + 2 * NP_)
        ((float*)sP)[x - 2 * NA_] = init_cp[x - 2 * NA_];
    __syncthreads();

    float px = -1.0f + (2.0f / (float)(W_ - 1)) * (float)x;
    float py = -1.0f + (2.0f / (float)(H_ - 1)) * (float)y;

    float ax = sW[NP_][0] + px * sW[NP_ + 1][0] + py * sW[NP_ + 2][0];
    float ay = sW[NP_][1] + px * sW[NP_ + 1][1] + py * sW[NP_ + 2][1];
    #pragma unroll
    for (int n = 0; n < NP_; ++n) {
        float dx = px - sP[n][0];
        float dy = py - sP[n][1];
        float d2 = dx * dx + dy * dy;
        float u  = d2 * logf(d2 + 1e-6f);
        ax += u * sW[n][0];
        ay += u * sW[n][1];
    }

    // bilinear sample, border clamp, align_corners=True
    float xf = fminf(fmaxf((ax + 1.0f) * 0.5f * (float)(W_ - 1), 0.0f), (float)(W_ - 1));
    float yf = fminf(fmaxf((ay + 1.0f) * 0.5f * (float)(H_ - 1), 0.0f), (float)(H_ - 1));
    float x0f = floorf(xf), y0f = floorf(yf);
    int x0 = (int)x0f, y0 = (int)y0f;
    int x1 = min(x0 + 1, W_ - 1);
    int y1 = min(y0 + 1, H_ - 1);
    float wx = xf - x0f, wy = yf - y0f;
    float omwx = 1.0f - wx, omwy = 1.0f - wy;

    int i00 = y0 * W_ + x0;
    int i01 = y0 * W_ + x1;
    int i10 = y1 * W_ + x0;
    int i11 = y1 * W_ + x1;

    const float* tb = t   + (size_t)b * C_ * HW_;
    float*       ob = out + (size_t)b * C_ * HW_ + y * W_ + x;
    #pragma unroll 4
    for (int c = 0; c < C_; ++c) {
        const float* tc = tb + (size_t)c * HW_;
        float top = tc[i00] * omwx + tc[i01] * wx;
        float bot = tc[i10] * omwx + tc[i11] * wx;
        ob[(size_t)c * HW_] = top * omwy + bot * wy;
    }
}

// ---------------------------------------------------------------------------
extern "C" void kernel_launch(void* const* d_in, const int* in_sizes, int n_in,
                              void* d_out, int out_size, void* d_ws, size_t ws_size,
                              hipStream_t stream) {
    const float* t       = (const float*)d_in[0];
    const float* rgb     = (const float*)d_in[1];
    const float* fc_w    = (const float*)d_in[2];
    const float* fc_b    = (const float*)d_in[3];
    const float* init_cp = (const float*)d_in[4];

    float* out    = (float*)d_out;
    float* cp_out = out + (size_t)B_ * C_ * HW_;   // tuple output #2

    float*  partial = (float*)d_ws;                    // 8192 f32 = 32 KB
    double* Wm      = (double*)((char*)d_ws + 32768);  // 8*28*2 f64

    mean_partial_kernel<<<B_ * 2 * C_ * PARTS_, 256, 0, stream>>>(t, rgb, partial);
    solve_kernel<<<1, 256, 0, stream>>>(partial, fc_w, fc_b, init_cp, cp_out, Wm);
    sample_kernel<<<B_ * H_, 256, 0, stream>>>(t, init_cp, Wm, out);
}